// Round 12
// baseline (2740.466 us; speedup 1.0000x reference)
//
#include <hip/hip_runtime.h>
#include <hip/hip_bf16.h>
#include <math.h>

typedef __attribute__((ext_vector_type(8))) short short8;
typedef __attribute__((ext_vector_type(4))) float f32x4;
typedef unsigned long long u64;

#define STEPS 512
#define BB 256      // batch
#define HH 256      // hidden
#define DD 131      // feature dim
#define XP 160      // x padded to 5*32
#define K0P 416     // layer0 K: 160 + 256
#define KS0 424     // W LDS stride (16B aligned, 2-way banks)
#define K1  512     // layer1 K
#define KS1 520
#define HS0 264     // L0 hstage stride (2-way banks)
#define HS1 520     // L1 hstage stride
#define RING 16
#define PO   8      // poison offset (slots ahead)
#define NGRP 8      // batch groups (32 rows each)
#define ROWS 32
#define SLOT_E (ROWS * HH)          // 8192 elems per ring slot
#define RGELEM (RING * SLOT_E)      // 131072 elems per group ring
#define POISON64 0x7F807F807F807F80ull

// ws bf16-elem offsets
#define OFF_W0E 0
#define OFF_W0D (OFF_W0E + 1024 * K0P)
#define OFF_W1E (OFF_W0D + 1024 * K0P)
#define OFF_W1D (OFF_W1E + 1024 * K1)
#define OFF_LW  (OFF_W1D + 1024 * K1)
#define OFF_XBF (OFF_LW + 160 * 256)
#define OFF_H0R (OFF_XBF + (size_t)STEPS * BB * XP)
#define OFF_H1R (OFF_H0R + (size_t)NGRP * RGELEM)
#define OFF_H1A (OFF_H1R + (size_t)NGRP * RGELEM)
#define OFF_BF16_END (OFF_H1A + (size_t)256 * BB * HH)

// dynamic LDS byte offsets
#define LDS_W_OFF  0                // 64 pcols x KS1 x 2B (worst) = 66560
#define LDS_HS_OFF 66560            // hstage double buffer (worst 2x32x520x2)
#define LDS_TOTAL  133120

__device__ __forceinline__ float rcp_(float x) { return __builtin_amdgcn_rcpf(x); }
__device__ __forceinline__ float fsigm(float x) { return rcp_(1.f + __expf(-x)); }
__device__ __forceinline__ float ftanh(float x) {
    float t = __expf(-2.f * fabsf(x));
    float r = (1.f - t) * rcp_(1.f + t);
    return copysignf(r, x);
}
__device__ __forceinline__ u64 aload(const u64* p) {
    return __hip_atomic_load(p, __ATOMIC_RELAXED, __HIP_MEMORY_SCOPE_AGENT);
}
__device__ __forceinline__ void astore(u64* p, u64 v) {
    __hip_atomic_store(p, v, __ATOMIC_RELAXED, __HIP_MEMORY_SCOPE_AGENT);
}

// ---------------- packing ----------------
// W0 packed rows p = ct*64 + g*16 + j  -> orig row g*256 + ct*16 + j
// K layout: [x 0..131 | pad ..160 | h 160..416]
__global__ __launch_bounds__(256) void pack_w0(const float* __restrict__ Wih,
                                               const float* __restrict__ Whh,
                                               __hip_bfloat16* __restrict__ dst) {
    int idx = blockIdx.x * 256 + threadIdx.x;       // 1024*416
    int p = idx / K0P, k = idx - p * K0P;
    int ct = p >> 6, local = p & 63, g = local >> 4, j = local & 15;
    int orow = g * 256 + ct * 16 + j;
    float v = 0.f;
    if (k < DD) v = Wih[orow * DD + k];
    else if (k >= XP) v = Whh[orow * HH + (k - XP)];
    dst[idx] = __float2bfloat16(v);
}

__global__ __launch_bounds__(256) void pack_w1(const float* __restrict__ Wih,
                                               const float* __restrict__ Whh,
                                               __hip_bfloat16* __restrict__ dst) {
    int idx = blockIdx.x * 256 + threadIdx.x;       // 1024*512
    int p = idx >> 9, k = idx & 511;
    int ct = p >> 6, local = p & 63, g = local >> 4, j = local & 15;
    int orow = g * 256 + ct * 16 + j;
    float v = (k < HH) ? Wih[orow * HH + k] : Whh[orow * HH + (k - HH)];
    dst[idx] = __float2bfloat16(v);
}

__global__ __launch_bounds__(256) void pack_bias(const float* __restrict__ bih,
                                                 const float* __restrict__ bhh,
                                                 float* __restrict__ dst) {
    int idx = blockIdx.x * 256 + threadIdx.x;
    if (idx < 1024) dst[idx] = bih[idx] + bhh[idx];
}

__global__ __launch_bounds__(256) void pack_xbf(const float* __restrict__ X,
                                                const float* __restrict__ Y,
                                                __hip_bfloat16* __restrict__ dst) {
    int idx = blockIdx.x * 256 + threadIdx.x;       // 512*256*160
    int kp = idx % XP;
    int rb = idx / XP;
    int b = rb & 255, s = rb >> 8;
    const float* src;
    if (s <= 256) src = X + ((size_t)s * BB + b) * DD;
    else          src = Y + ((size_t)(s - 257) * BB + b) * DD;
    dst[idx] = __float2bfloat16(kp < DD ? src[kp] : 0.f);
}

__global__ __launch_bounds__(256) void pack_linw(const float* __restrict__ linW,
                                                 __hip_bfloat16* __restrict__ dst) {
    int idx = blockIdx.x * 256 + threadIdx.x;       // 160*256
    int j = idx >> 8, k = idx & 255;
    dst[idx] = __float2bfloat16(j < DD ? linW[j * HH + k] : 0.f);
}

__global__ __launch_bounds__(256) void pack_linb(const float* __restrict__ linb,
                                                 float* __restrict__ dst) {
    int idx = threadIdx.x;
    if (idx < 160) dst[idx] = (idx < DD) ? linb[idx] : -1.0e30f;
}

// rings: poison everything except last slot (= step -1 zero state); acks=0
__global__ __launch_bounds__(256) void init_rings(u64* __restrict__ rings,
                                                  int* __restrict__ acks) {
    int idx = blockIdx.x * 256 + threadIdx.x;       // 524288 u64 (both rings)
    if (idx < 2 * NGRP * (RGELEM / 4)) {
        int slot = (idx >> 11) & (RING - 1);        // 2048 u64 per slot
        rings[idx] = (slot == RING - 1) ? 0ull : POISON64;
    }
    if (idx < 256) acks[idx] = 0;
}

// ---------------- persistent pipelined LSTM ----------------
// 256 WGs x 512 thr. wg = [group(8)][layer(2)][ct(16)]; group g owns batch
// rows [g*32,+32). Wave roles: waves 0-1 compute (gate-major acc[4], c in
// VGPRs), waves 2-7 poison-poll inputs into double-buffered hstage.
// L0: one barrier/step (x-GEMM overlaps poll). L1: TWO barriers/step --
// phase 1 stages h1[s-1] (early), then h1-part GEMM overlaps the h0[s] poll,
// phase 2 finishes h0-part + gates + publish. Poll batches capped at 6
// addresses/thread (detect cost scales with per-thread poll count).
__global__ __launch_bounds__(512, 1) void lstm_persistent(
    const __hip_bfloat16* __restrict__ wsb,
    const float* __restrict__ bsum,
    __hip_bfloat16* __restrict__ h0ring,
    __hip_bfloat16* __restrict__ h1ring,
    __hip_bfloat16* __restrict__ h1all,
    int* __restrict__ acks) {
    extern __shared__ __align__(16) char lds[];
    __hip_bfloat16* Wlds = (__hip_bfloat16*)(lds + LDS_W_OFF);
    __hip_bfloat16* hst  = (__hip_bfloat16*)(lds + LDS_HS_OFF);

    const int tid = threadIdx.x;
    const int wg = blockIdx.x;
    const int xg = wg >> 5;
    const int slot_id = wg & 31;
    const int layer = slot_id >> 4;
    const int ct = slot_id & 15;
    const int lane = tid & 63;
    const int mt = tid >> 6;        // compute waves: M-tile 0/1
    const int lrow = lane & 15;
    const int lk8 = (lane >> 4) * 8;

    const int K  = layer ? K1 : K0P;
    const int KS = layer ? KS1 : KS0;
    const int HS = layer ? HS1 : HS0;
    int* ackp = acks + xg * 32;

    auto load_w = [&](int ph2) {
        const __hip_bfloat16* src = wsb +
            (layer ? (ph2 ? OFF_W1D : OFF_W1E) : (ph2 ? OFF_W0D : OFF_W0E)) +
            (size_t)ct * 64 * K;
        const int KC = K >> 3;
        for (int e = tid; e < 64 * KC; e += 512) {
            int p = e / KC, kc = e - p * KC;
            *(short8*)&Wlds[p * KS + kc * 8] =
                *(const short8*)&src[(size_t)p * K + kc * 8];
        }
    };
    load_w(0);

    const int jcol = ct * 16 + lrow;       // compute lanes' output column
    float br[2][4];
    #pragma unroll
    for (int ph = 0; ph < 2; ++ph)
        #pragma unroll
        for (int g = 0; g < 4; ++g)
            br[ph][g] = bsum[ph * 2048 + layer * 1024 + g * 256 + jcol];
    f32x4 creg = {0.f, 0.f, 0.f, 0.f};

    const __hip_bfloat16* Xbf = wsb + OFF_XBF;
    __hip_bfloat16* h0g = h0ring + (size_t)xg * RGELEM;
    __hip_bfloat16* h1g = h1ring + (size_t)xg * RGELEM;
    __hip_bfloat16* ringw = layer ? h1g : h0g;
    const int arow = mt * 16 + lrow;
    __syncthreads();

    for (int s = 0; s < STEPS; ++s) {
        const int ph = s >> 8;
        const bool defer_x = (s == 256);   // W reloads at the barrier
        f32x4 acc[4];
        short8 xv[5];

        // =================== phase 1 (before barrier A1) ===================
        if (tid < 128) {
            #pragma unroll
            for (int g = 0; g < 4; ++g) acc[g] = (f32x4){0.f, 0.f, 0.f, 0.f};
            if (layer == 0) {
                // x fragment loads + x-part GEMM, overlapped with poll
                const short8* xp = (const short8*)
                    &Xbf[((size_t)s * BB + xg * ROWS + arow) * XP];
                #pragma unroll
                for (int kt = 0; kt < 5; ++kt) xv[kt] = xp[kt * 4 + (lk8 >> 3)];
                if (!defer_x) {
                    #pragma unroll
                    for (int kt = 0; kt < 5; ++kt)
                        #pragma unroll
                        for (int g = 0; g < 4; ++g) {
                            short8 w = *(const short8*)
                                &Wlds[(g * 16 + lrow) * KS0 + kt * 32 + lk8];
                            acc[g] = __builtin_amdgcn_mfma_f32_16x16x32_bf16(
                                xv[kt], w, acc[g], 0, 0, 0);
                        }
                }
            }
        } else {
            const int ptid = tid - 128;              // 0..383
            __hip_bfloat16* hs = hst + (s & 1) * 32 * HS;
            if (layer == 0) {
                // stage full h0[s-1] slot (2048 pkts, <=6/thread)
                const u64* src = (const u64*)(h0g +
                    (size_t)((s + RING - 1) & (RING - 1)) * SLOT_E);
                u64 v[6];
                unsigned pend = 0;
                #pragma unroll
                for (int i = 0; i < 6; ++i)
                    if (ptid + i * 384 < 2048) pend |= (1u << i);
                int guard = 0;
                while (pend) {
                    #pragma unroll
                    for (int i = 0; i < 6; ++i)
                        if (pend & (1u << i)) v[i] = aload(src + ptid + i * 384);
                    unsigned np = 0;
                    #pragma unroll
                    for (int i = 0; i < 6; ++i)
                        if ((pend & (1u << i)) &&
                            ((v[i] & 0xFFFFull) == 0x7F80ull)) np |= (1u << i);
                    pend = np;
                    if (pend) {
                        __builtin_amdgcn_s_sleep(1);
                        if (++guard > 65536) break;   // fail visibly, not hang
                    }
                }
                #pragma unroll
                for (int i = 0; i < 6; ++i) {
                    int p = ptid + i * 384;
                    if (p < 2048) {
                        int row = p >> 6, c = p & 63;
                        *(u64*)&hs[row * HS0 + c * 4] = v[i];
                    }
                }
                // backpressure (off compute path): L1 staged h0[s-8]?
                if (ptid == 383) {
                    int tgt = 16 * (s - (PO - 1));
                    if (tgt > 0) {
                        int guard2 = 0;
                        while (__hip_atomic_load(ackp, __ATOMIC_RELAXED,
                                                 __HIP_MEMORY_SCOPE_AGENT) < tgt) {
                            __builtin_amdgcn_s_sleep(1);
                            if (++guard2 > 65536) break;
                        }
                    }
                }
            } else {
                // stage h1[s-1] slot (2048 pkts) into upper half of hs row
                const u64* s1 = (const u64*)(h1g +
                    (size_t)((s + RING - 1) & (RING - 1)) * SLOT_E);
                u64 v[6];
                unsigned pend = 0;
                #pragma unroll
                for (int i = 0; i < 6; ++i)
                    if (ptid + i * 384 < 2048) pend |= (1u << i);
                int guard = 0;
                while (pend) {
                    #pragma unroll
                    for (int i = 0; i < 6; ++i)
                        if (pend & (1u << i)) v[i] = aload(s1 + ptid + i * 384);
                    unsigned np = 0;
                    #pragma unroll
                    for (int i = 0; i < 6; ++i)
                        if ((pend & (1u << i)) &&
                            ((v[i] & 0xFFFFull) == 0x7F80ull)) np |= (1u << i);
                    pend = np;
                    if (pend) {
                        __builtin_amdgcn_s_sleep(1);
                        if (++guard > 65536) break;
                    }
                }
                #pragma unroll
                for (int i = 0; i < 6; ++i) {
                    int p = ptid + i * 384;
                    if (p < 2048) {
                        int row = p >> 6, c = p & 63;
                        *(u64*)&hs[row * HS1 + 256 + c * 4] = v[i];
                    }
                }
            }
        }
        __syncthreads();                    // [A1]

        // =================== phase 2 (A1 .. A2) ===========================
        if (tid < 128) {
            if (layer == 1) {
                // h1-part GEMM (kt 8..15) overlaps the h0[s] poll below
                const __hip_bfloat16* hs = hst + (s & 1) * 32 * HS1;
                #pragma unroll
                for (int kt = 8; kt < 16; ++kt) {
                    short8 a = *(const short8*)&hs[arow * HS1 + kt * 32 + lk8];
                    #pragma unroll
                    for (int g = 0; g < 4; ++g) {
                        short8 w = *(const short8*)
                            &Wlds[(g * 16 + lrow) * KS1 + kt * 32 + lk8];
                        acc[g] = __builtin_amdgcn_mfma_f32_16x16x32_bf16(
                            a, w, acc[g], 0, 0, 0);
                    }
                }
            }
        } else if (layer == 1) {
            // poll h0[s] (published by L0 mid-period), stage lower half
            const int ptid = tid - 128;
            __hip_bfloat16* hs = hst + (s & 1) * 32 * HS1;
            const u64* s0 = (const u64*)(h0g +
                (size_t)(s & (RING - 1)) * SLOT_E);
            u64 v[6];
            unsigned pend = 0;
            #pragma unroll
            for (int i = 0; i < 6; ++i)
                if (ptid + i * 384 < 2048) pend |= (1u << i);
            int guard = 0;
            while (pend) {
                #pragma unroll
                for (int i = 0; i < 6; ++i)
                    if (pend & (1u << i)) v[i] = aload(s0 + ptid + i * 384);
                unsigned np = 0;
                #pragma unroll
                for (int i = 0; i < 6; ++i)
                    if ((pend & (1u << i)) &&
                        ((v[i] & 0xFFFFull) == 0x7F80ull)) np |= (1u << i);
                pend = np;
                if (pend) {
                    __builtin_amdgcn_s_sleep(1);
                    if (++guard > 65536) break;
                }
            }
            #pragma unroll
            for (int i = 0; i < 6; ++i) {
                int p = ptid + i * 384;
                if (p < 2048) {
                    int row = p >> 6, c = p & 63;
                    *(u64*)&hs[row * HS1 + c * 4] = v[i];
                }
            }
        }
        __syncthreads();                    // [A2]
        if (s == 256) { load_w(1); __syncthreads(); }

        // =================== phase 3 (after A2) ===========================
        if (tid < 128) {
            if (layer == 1 && tid == 0)     // ack: h0[s] consumed from ring
                __hip_atomic_fetch_add(ackp, 1, __ATOMIC_RELAXED,
                                       __HIP_MEMORY_SCOPE_AGENT);
            const __hip_bfloat16* hs = hst + (s & 1) * 32 * HS;
            if (layer == 0) {
                if (defer_x) {
                    #pragma unroll
                    for (int kt = 0; kt < 5; ++kt)
                        #pragma unroll
                        for (int g = 0; g < 4; ++g) {
                            short8 w = *(const short8*)
                                &Wlds[(g * 16 + lrow) * KS0 + kt * 32 + lk8];
                            acc[g] = __builtin_amdgcn_mfma_f32_16x16x32_bf16(
                                xv[kt], w, acc[g], 0, 0, 0);
                        }
                }
                #pragma unroll
                for (int kt = 0; kt < 8; ++kt) {
                    short8 a = *(const short8*)&hs[arow * HS0 + kt * 32 + lk8];
                    #pragma unroll
                    for (int g = 0; g < 4; ++g) {
                        short8 w = *(const short8*)
                            &Wlds[(g * 16 + lrow) * KS0 + (5 + kt) * 32 + lk8];
                        acc[g] = __builtin_amdgcn_mfma_f32_16x16x32_bf16(
                            a, w, acc[g], 0, 0, 0);
                    }
                }
            } else {
                // h0-part GEMM (kt 0..7); h1 part already accumulated
                #pragma unroll
                for (int kt = 0; kt < 8; ++kt) {
                    short8 a = *(const short8*)&hs[arow * HS1 + kt * 32 + lk8];
                    #pragma unroll
                    for (int g = 0; g < 4; ++g) {
                        short8 w = *(const short8*)
                            &Wlds[(g * 16 + lrow) * KS1 + kt * 32 + lk8];
                        acc[g] = __builtin_amdgcn_mfma_f32_16x16x32_bf16(
                            a, w, acc[g], 0, 0, 0);
                    }
                }
            }

            // ---- gates fused in-lane (4 rows per lane) ----
            unsigned short hu[4];
            #pragma unroll
            for (int r = 0; r < 4; ++r) {
                float zi = acc[0][r] + br[ph][0];
                float zf = acc[1][r] + br[ph][1];
                float zg = acc[2][r] + br[ph][2];
                float zo = acc[3][r] + br[ph][3];
                float ig = fsigm(zi), fg = fsigm(zf), og = fsigm(zo);
                float cn = fg * creg[r] + ig * ftanh(zg);
                creg[r] = cn;
                union { __hip_bfloat16 b; unsigned short u; } cvt;
                cvt.b = __float2bfloat16(og * ftanh(cn));
                hu[r] = cvt.u;
            }

            // ---- in-wave transpose -> u64 packets; publish + poison ----
            {
                const int m = lane & 15, g16 = lane >> 4;
                const int srcbase = g16 * 16 + 4 * (m & 3);
                const int myslot = m >> 2;
                unsigned short pa = 0, pb = 0, pc = 0, pd = 0;
                #pragma unroll
                for (int rr = 0; rr < 4; ++rr) {
                    int q0 = __shfl((int)hu[rr], srcbase + 0, 64);
                    int q1 = __shfl((int)hu[rr], srcbase + 1, 64);
                    int q2 = __shfl((int)hu[rr], srcbase + 2, 64);
                    int q3 = __shfl((int)hu[rr], srcbase + 3, 64);
                    if (myslot == rr) {
                        pa = (unsigned short)q0; pb = (unsigned short)q1;
                        pc = (unsigned short)q2; pd = (unsigned short)q3;
                    }
                }
                u64 pkt = (u64)pa | ((u64)pb << 16) | ((u64)pc << 32)
                        | ((u64)pd << 48);
                const int prow = mt * 16 + g16 * 4 + myslot;   // 0..31
                const int pq = m & 3;
                astore((u64*)(ringw + (size_t)(s & (RING - 1)) * SLOT_E)
                       + prow * 64 + ct * 4 + pq, pkt);
                astore((u64*)(ringw + (size_t)((s + PO) & (RING - 1)) * SLOT_E)
                       + prow * 64 + ct * 4 + pq, POISON64);
                if (layer == 1 && s >= 256)
                    *(u64*)&h1all[((size_t)(s - 256) * BB + xg * ROWS + prow) * HH
                                  + ct * 16 + pq * 4] = pkt;
            }
        }
    }
}

// ---------------- MFMA emit: logits + log_softmax ----------------
__global__ __launch_bounds__(256) void emit_mfma(
    const __hip_bfloat16* __restrict__ h1all,
    const __hip_bfloat16* __restrict__ lW,
    const float* __restrict__ lb,
    float* __restrict__ out) {
    __shared__ float lbs[160];
    const int tid = threadIdx.x;
    const int wv = tid >> 6, lane = tid & 63;
    const int lrow = lane & 15, lk8 = (lane >> 4) * 8, crow = (lane >> 4) * 4;
    const int row0 = blockIdx.x * 64;
    if (tid < 160) lbs[tid] = lb[tid];
    __syncthreads();

    f32x4 acc[10];
    #pragma unroll
    for (int f = 0; f < 10; ++f) acc[f] = (f32x4){0.f, 0.f, 0.f, 0.f};
    const int arow = row0 + wv * 16 + lrow;
    #pragma unroll
    for (int kt = 0; kt < 8; ++kt) {
        short8 a = *reinterpret_cast<const short8*>(
            &h1all[(size_t)arow * HH + kt * 32 + lk8]);
        #pragma unroll
        for (int f = 0; f < 10; ++f) {
            short8 w = *reinterpret_cast<const short8*>(
                &lW[(size_t)(f * 16 + lrow) * HH + kt * 32 + lk8]);
            acc[f] = __builtin_amdgcn_mfma_f32_16x16x32_bf16(a, w, acc[f], 0, 0, 0);
        }
    }
    #pragma unroll
    for (int r = 0; r < 4; ++r) {
        float m = -3.0e38f;
        #pragma unroll
        for (int f = 0; f < 10; ++f) m = fmaxf(m, acc[f][r] + lbs[f * 16 + lrow]);
        #pragma unroll
        for (int d = 1; d < 16; d <<= 1) m = fmaxf(m, __shfl_xor(m, d, 64));
        float ss = 0.f;
        #pragma unroll
        for (int f = 0; f < 10; ++f) ss += __expf(acc[f][r] + lbs[f * 16 + lrow] - m);
        #pragma unroll
        for (int d = 1; d < 16; d <<= 1) ss += __shfl_xor(ss, d, 64);
        float lse = m + logf(ss);
        int grow = row0 + wv * 16 + crow + r;
        #pragma unroll
        for (int f = 0; f < 9; ++f) {
            int j = f * 16 + lrow;
            if (j < DD)
                out[(size_t)grow * DD + j] = acc[f][r] + lbs[j] - lse;
        }
    }
}

extern "C" void kernel_launch(void* const* d_in, const int* in_sizes, int n_in,
                              void* d_out, int out_size, void* d_ws, size_t ws_size,
                              hipStream_t stream) {
    const float* X     = (const float*)d_in[0];
    const float* Y     = (const float*)d_in[1];
    const float* eWih0 = (const float*)d_in[2];
    const float* eWhh0 = (const float*)d_in[3];
    const float* ebih0 = (const float*)d_in[4];
    const float* ebhh0 = (const float*)d_in[5];
    const float* eWih1 = (const float*)d_in[6];
    const float* eWhh1 = (const float*)d_in[7];
    const float* ebih1 = (const float*)d_in[8];
    const float* ebhh1 = (const float*)d_in[9];
    const float* dWih0 = (const float*)d_in[10];
    const float* dWhh0 = (const float*)d_in[11];
    const float* dbih0 = (const float*)d_in[12];
    const float* dbhh0 = (const float*)d_in[13];
    const float* dWih1 = (const float*)d_in[14];
    const float* dWhh1 = (const float*)d_in[15];
    const float* dbih1 = (const float*)d_in[16];
    const float* dbhh1 = (const float*)d_in[17];
    const float* linW  = (const float*)d_in[18];
    const float* linb  = (const float*)d_in[19];
    float* out = (float*)d_out;

    __hip_bfloat16* wsb = (__hip_bfloat16*)d_ws;
    float* freg  = (float*)(wsb + OFF_BF16_END);
    float* bsum  = freg;                       // 4096 f32
    float* linbp = freg + 4096;                // 192
    int*   acks  = (int*)(freg + 4096 + 192);  // 256 ints (128B/group)

    pack_w0<<<dim3(1664), dim3(256), 0, stream>>>(eWih0, eWhh0, wsb + OFF_W0E);
    pack_w0<<<dim3(1664), dim3(256), 0, stream>>>(dWih0, dWhh0, wsb + OFF_W0D);
    pack_w1<<<dim3(2048), dim3(256), 0, stream>>>(eWih1, eWhh1, wsb + OFF_W1E);
    pack_w1<<<dim3(2048), dim3(256), 0, stream>>>(dWih1, dWhh1, wsb + OFF_W1D);
    pack_bias<<<dim3(4), dim3(256), 0, stream>>>(ebih0, ebhh0, bsum + 0);
    pack_bias<<<dim3(4), dim3(256), 0, stream>>>(ebih1, ebhh1, bsum + 1024);
    pack_bias<<<dim3(4), dim3(256), 0, stream>>>(dbih0, dbhh0, bsum + 2048);
    pack_bias<<<dim3(4), dim3(256), 0, stream>>>(dbih1, dbhh1, bsum + 3072);
    pack_xbf<<<dim3(81920), dim3(256), 0, stream>>>(X, Y, wsb + OFF_XBF);
    pack_linw<<<dim3(160), dim3(256), 0, stream>>>(linW, wsb + OFF_LW);
    pack_linb<<<dim3(1), dim3(256), 0, stream>>>(linb, linbp);
    init_rings<<<dim3(2048), dim3(256), 0, stream>>>((u64*)(wsb + OFF_H0R), acks);

    hipFuncSetAttribute((const void*)lstm_persistent,
                        hipFuncAttributeMaxDynamicSharedMemorySize, LDS_TOTAL);
    lstm_persistent<<<dim3(256), dim3(512), LDS_TOTAL, stream>>>(
        wsb, bsum, wsb + OFF_H0R, wsb + OFF_H1R, wsb + OFF_H1A, acks);

    emit_mfma<<<dim3(1024), dim3(256), 0, stream>>>(wsb + OFF_H1A, wsb + OFF_LW,
                                                    linbp, out);
}

// Round 13
// 2444.672 us; speedup vs baseline: 1.1210x; 1.1210x over previous
//
#include <hip/hip_runtime.h>
#include <hip/hip_bf16.h>
#include <math.h>

typedef __attribute__((ext_vector_type(8))) short short8;
typedef __attribute__((ext_vector_type(4))) float f32x4;
typedef unsigned long long u64;
typedef __attribute__((ext_vector_type(2))) unsigned long long u64x2;

#define STEPS 512
#define BB 256      // batch
#define HH 256      // hidden
#define DD 131      // feature dim
#define XP 160      // x padded to 5*32
#define K0P 416     // layer0 K: 160 + 256
#define KS0 424     // W LDS stride (16B aligned, 2-way banks)
#define K1  512     // layer1 K
#define KS1 520
#define HS0 264     // L0 hstage stride (2-way banks)
#define HS1 520     // L1 hstage stride
#define RING 16
#define PO   8      // poison offset (slots ahead)
#define NGRP 8      // batch groups (32 rows each)
#define ROWS 32
#define SLOT_E (ROWS * HH)          // 8192 elems per ring slot
#define RGELEM (RING * SLOT_E)      // 131072 elems per group ring
#define POISON64 0x7F807F807F807F80ull

// ws bf16-elem offsets
#define OFF_W0E 0
#define OFF_W0D (OFF_W0E + 1024 * K0P)
#define OFF_W1E (OFF_W0D + 1024 * K0P)
#define OFF_W1D (OFF_W1E + 1024 * K1)
#define OFF_LW  (OFF_W1D + 1024 * K1)
#define OFF_XBF (OFF_LW + 160 * 256)
#define OFF_H0R (OFF_XBF + (size_t)STEPS * BB * XP)
#define OFF_H1R (OFF_H0R + (size_t)NGRP * RGELEM)
#define OFF_H1A (OFF_H1R + (size_t)NGRP * RGELEM)
#define OFF_BF16_END (OFF_H1A + (size_t)256 * BB * HH)

// dynamic LDS byte offsets
#define LDS_W_OFF  0                // 64 pcols x KS1 x 2B (worst) = 66560
#define LDS_HS_OFF 66560            // hstage double buffer (worst 2x32x520x2)
#define LDS_TOTAL  133120

__device__ __forceinline__ float rcp_(float x) { return __builtin_amdgcn_rcpf(x); }
__device__ __forceinline__ float fsigm(float x) { return rcp_(1.f + __expf(-x)); }
__device__ __forceinline__ float ftanh(float x) {
    float t = __expf(-2.f * fabsf(x));
    float r = (1.f - t) * rcp_(1.f + t);
    return copysignf(r, x);
}
__device__ __forceinline__ void astore(u64* p, u64 v) {
    __hip_atomic_store(p, v, __ATOMIC_RELAXED, __HIP_MEMORY_SCOPE_AGENT);
}
// 16B poll load on the same sc0+sc1 (MALL coherence) path as the atomics.
// Each 8B half was written by a single 8B store => halves cannot tear.
__device__ __forceinline__ void pload(const u64* p, u64x2& r) {
    asm volatile("global_load_dwordx4 %0, %1, off sc0 sc1" : "=v"(r) : "v"(p));
}
__device__ __forceinline__ void pll_drain() {
    asm volatile("s_waitcnt vmcnt(0)" ::: "memory");
    __builtin_amdgcn_sched_barrier(0);
}

// ---------------- packing ----------------
// W0 packed rows p = ct*64 + g*16 + j  -> orig row g*256 + ct*16 + j
// K layout: [x 0..131 | pad ..160 | h 160..416]
__global__ __launch_bounds__(256) void pack_w0(const float* __restrict__ Wih,
                                               const float* __restrict__ Whh,
                                               __hip_bfloat16* __restrict__ dst) {
    int idx = blockIdx.x * 256 + threadIdx.x;       // 1024*416
    int p = idx / K0P, k = idx - p * K0P;
    int ct = p >> 6, local = p & 63, g = local >> 4, j = local & 15;
    int orow = g * 256 + ct * 16 + j;
    float v = 0.f;
    if (k < DD) v = Wih[orow * DD + k];
    else if (k >= XP) v = Whh[orow * HH + (k - XP)];
    dst[idx] = __float2bfloat16(v);
}

__global__ __launch_bounds__(256) void pack_w1(const float* __restrict__ Wih,
                                               const float* __restrict__ Whh,
                                               __hip_bfloat16* __restrict__ dst) {
    int idx = blockIdx.x * 256 + threadIdx.x;       // 1024*512
    int p = idx >> 9, k = idx & 511;
    int ct = p >> 6, local = p & 63, g = local >> 4, j = local & 15;
    int orow = g * 256 + ct * 16 + j;
    float v = (k < HH) ? Wih[orow * HH + k] : Whh[orow * HH + (k - HH)];
    dst[idx] = __float2bfloat16(v);
}

__global__ __launch_bounds__(256) void pack_bias(const float* __restrict__ bih,
                                                 const float* __restrict__ bhh,
                                                 float* __restrict__ dst) {
    int idx = blockIdx.x * 256 + threadIdx.x;
    if (idx < 1024) dst[idx] = bih[idx] + bhh[idx];
}

__global__ __launch_bounds__(256) void pack_xbf(const float* __restrict__ X,
                                                const float* __restrict__ Y,
                                                __hip_bfloat16* __restrict__ dst) {
    int idx = blockIdx.x * 256 + threadIdx.x;       // 512*256*160
    int kp = idx % XP;
    int rb = idx / XP;
    int b = rb & 255, s = rb >> 8;
    const float* src;
    if (s <= 256) src = X + ((size_t)s * BB + b) * DD;
    else          src = Y + ((size_t)(s - 257) * BB + b) * DD;
    dst[idx] = __float2bfloat16(kp < DD ? src[kp] : 0.f);
}

__global__ __launch_bounds__(256) void pack_linw(const float* __restrict__ linW,
                                                 __hip_bfloat16* __restrict__ dst) {
    int idx = blockIdx.x * 256 + threadIdx.x;       // 160*256
    int j = idx >> 8, k = idx & 255;
    dst[idx] = __float2bfloat16(j < DD ? linW[j * HH + k] : 0.f);
}

__global__ __launch_bounds__(256) void pack_linb(const float* __restrict__ linb,
                                                 float* __restrict__ dst) {
    int idx = threadIdx.x;
    if (idx < 160) dst[idx] = (idx < DD) ? linb[idx] : -1.0e30f;
}

// rings: poison everything except last slot (= step -1 zero state); acks=0
__global__ __launch_bounds__(256) void init_rings(u64* __restrict__ rings,
                                                  int* __restrict__ acks) {
    int idx = blockIdx.x * 256 + threadIdx.x;       // 524288 u64 (both rings)
    if (idx < 2 * NGRP * (RGELEM / 4)) {
        int slot = (idx >> 11) & (RING - 1);        // 2048 u64 per slot
        rings[idx] = (slot == RING - 1) ? 0ull : POISON64;
    }
    if (idx < 256) acks[idx] = 0;
}

// ---------------- persistent pipelined LSTM ----------------
// 256 WGs x 512 thr. wg = [group(8)][layer(2)][ct(16)]; group g owns batch
// rows [g*32,+32). Wave roles: waves 0-1 compute (gate-major acc[4], c in
// VGPRs), waves 2-7 poison-poll inputs (16B loads, 2 packets each, no sleep)
// into double-buffered hstage. One barrier per step. h published as u64
// packets built by a 16-shfl in-wave transpose; poison stays per-lane u64
// (same-thread same-address ordering with the step-s+8 data store).
__global__ __launch_bounds__(512, 1) void lstm_persistent(
    const __hip_bfloat16* __restrict__ wsb,
    const float* __restrict__ bsum,
    __hip_bfloat16* __restrict__ h0ring,
    __hip_bfloat16* __restrict__ h1ring,
    __hip_bfloat16* __restrict__ h1all,
    int* __restrict__ acks) {
    extern __shared__ __align__(16) char lds[];
    __hip_bfloat16* Wlds = (__hip_bfloat16*)(lds + LDS_W_OFF);
    __hip_bfloat16* hst  = (__hip_bfloat16*)(lds + LDS_HS_OFF);

    const int tid = threadIdx.x;
    const int wg = blockIdx.x;
    const int xg = wg >> 5;
    const int slot_id = wg & 31;
    const int layer = slot_id >> 4;
    const int ct = slot_id & 15;
    const int lane = tid & 63;
    const int mt = tid >> 6;        // compute waves: M-tile 0/1
    const int lrow = lane & 15;
    const int lk8 = (lane >> 4) * 8;

    const int K  = layer ? K1 : K0P;
    const int KS = layer ? KS1 : KS0;
    const int HS = layer ? HS1 : HS0;
    int* ackp = acks + xg * 32;

    auto load_w = [&](int ph2) {
        const __hip_bfloat16* src = wsb +
            (layer ? (ph2 ? OFF_W1D : OFF_W1E) : (ph2 ? OFF_W0D : OFF_W0E)) +
            (size_t)ct * 64 * K;
        const int KC = K >> 3;
        for (int e = tid; e < 64 * KC; e += 512) {
            int p = e / KC, kc = e - p * KC;
            *(short8*)&Wlds[p * KS + kc * 8] =
                *(const short8*)&src[(size_t)p * K + kc * 8];
        }
    };
    load_w(0);

    const int jcol = ct * 16 + lrow;       // compute lanes' output column
    float br[2][4];
    #pragma unroll
    for (int ph = 0; ph < 2; ++ph)
        #pragma unroll
        for (int g = 0; g < 4; ++g)
            br[ph][g] = bsum[ph * 2048 + layer * 1024 + g * 256 + jcol];
    f32x4 creg = {0.f, 0.f, 0.f, 0.f};

    const __hip_bfloat16* Xbf = wsb + OFF_XBF;
    __hip_bfloat16* h0g = h0ring + (size_t)xg * RGELEM;
    __hip_bfloat16* h1g = h1ring + (size_t)xg * RGELEM;
    __hip_bfloat16* ringw = layer ? h1g : h0g;
    const int arow = mt * 16 + lrow;
    __syncthreads();

    for (int s = 0; s < STEPS; ++s) {
        const int ph = s >> 8;
        const bool defer_x = (s == 256);   // W reloads at the barrier
        f32x4 acc[4];
        short8 xv[5];

        if (tid < 128) {
            // -------- compute waves: x-part overlapped with polling --------
            #pragma unroll
            for (int g = 0; g < 4; ++g) acc[g] = (f32x4){0.f, 0.f, 0.f, 0.f};
            if (layer == 0) {
                const short8* xp = (const short8*)
                    &Xbf[((size_t)s * BB + xg * ROWS + arow) * XP];
                #pragma unroll
                for (int kt = 0; kt < 5; ++kt) xv[kt] = xp[kt * 4 + (lk8 >> 3)];
                if (!defer_x) {
                    #pragma unroll
                    for (int kt = 0; kt < 5; ++kt)
                        #pragma unroll
                        for (int g = 0; g < 4; ++g) {
                            short8 w = *(const short8*)
                                &Wlds[(g * 16 + lrow) * KS0 + kt * 32 + lk8];
                            acc[g] = __builtin_amdgcn_mfma_f32_16x16x32_bf16(
                                xv[kt], w, acc[g], 0, 0, 0);
                        }
                }
            }
        } else {
            // -------- poller waves: stage step-s inputs into hst[s&1] ------
            const int ptid = tid - 128;              // 0..383
            __hip_bfloat16* hs = hst + (s & 1) * 32 * HS;
            if (layer == 0) {
                // 1024 x16B loads cover the 2048-packet h0[s-1] slot
                const u64* src = (const u64*)(h0g +
                    (size_t)((s + RING - 1) & (RING - 1)) * SLOT_E);
                u64x2 v[3];
                unsigned pend = 0;
                #pragma unroll
                for (int i = 0; i < 3; ++i)
                    if (ptid + i * 384 < 1024) pend |= (1u << i);
                int guard = 0;
                while (pend) {
                    #pragma unroll
                    for (int i = 0; i < 3; ++i)
                        if (pend & (1u << i))
                            pload(src + 2 * (ptid + i * 384), v[i]);
                    pll_drain();
                    unsigned np = 0;
                    #pragma unroll
                    for (int i = 0; i < 3; ++i)
                        if ((pend & (1u << i)) &&
                            (((v[i][0] & 0xFFFFull) == 0x7F80ull) ||
                             ((v[i][1] & 0xFFFFull) == 0x7F80ull)))
                            np |= (1u << i);
                    pend = np;
                    if (pend && ++guard > 65536) break;  // fail visibly
                }
                #pragma unroll
                for (int i = 0; i < 3; ++i) {
                    int q = ptid + i * 384;
                    if (q < 1024)
                        *(u64x2*)&hs[(q >> 5) * HS0 + (q & 31) * 8] = v[i];
                }
                // backpressure (off compute path): L1 staged h0[s-8]?
                if (ptid == 383) {
                    int tgt = 16 * (s - (PO - 1));
                    if (tgt > 0) {
                        int guard2 = 0;
                        while (__hip_atomic_load(ackp, __ATOMIC_RELAXED,
                                                 __HIP_MEMORY_SCOPE_AGENT) < tgt) {
                            __builtin_amdgcn_s_sleep(1);
                            if (++guard2 > 65536) break;
                        }
                    }
                }
            } else {
                const u64* s0 = (const u64*)(h0g +
                    (size_t)(s & (RING - 1)) * SLOT_E);
                const u64* s1 = (const u64*)(h1g +
                    (size_t)((s + RING - 1) & (RING - 1)) * SLOT_E);
                u64x2 v0[3], v1[3];
                unsigned pend = 0;
                #pragma unroll
                for (int i = 0; i < 3; ++i)
                    if (ptid + i * 384 < 1024) pend |= (0x101u << i);
                int guard = 0;
                while (pend) {
                    #pragma unroll
                    for (int i = 0; i < 3; ++i) {
                        if (pend & (1u << i))
                            pload(s0 + 2 * (ptid + i * 384), v0[i]);
                        if (pend & (0x100u << i))
                            pload(s1 + 2 * (ptid + i * 384), v1[i]);
                    }
                    pll_drain();
                    unsigned np = 0;
                    #pragma unroll
                    for (int i = 0; i < 3; ++i) {
                        if ((pend & (1u << i)) &&
                            (((v0[i][0] & 0xFFFFull) == 0x7F80ull) ||
                             ((v0[i][1] & 0xFFFFull) == 0x7F80ull)))
                            np |= (1u << i);
                        if ((pend & (0x100u << i)) &&
                            (((v1[i][0] & 0xFFFFull) == 0x7F80ull) ||
                             ((v1[i][1] & 0xFFFFull) == 0x7F80ull)))
                            np |= (0x100u << i);
                    }
                    pend = np;
                    if (pend && ++guard > 65536) break;
                }
                // hstage row: elems 0..255 = h0[s], 256..511 = h1[s-1]
                #pragma unroll
                for (int i = 0; i < 3; ++i) {
                    int q = ptid + i * 384;
                    if (q < 1024) {
                        *(u64x2*)&hs[(q >> 5) * HS1 + (q & 31) * 8] = v0[i];
                        *(u64x2*)&hs[(q >> 5) * HS1 + 256 + (q & 31) * 8] = v1[i];
                    }
                }
            }
        }
        __syncthreads();                    // [A] hst[s&1] staged
        if (s == 256) { load_w(1); __syncthreads(); }

        if (tid < 128) {
            if (layer == 1 && tid == 0)     // ack: h0[s] consumed from ring
                __hip_atomic_fetch_add(ackp, 1, __ATOMIC_RELAXED,
                                       __HIP_MEMORY_SCOPE_AGENT);
            const __hip_bfloat16* hs = hst + (s & 1) * 32 * HS;
            if (layer == 0) {
                if (defer_x) {
                    #pragma unroll
                    for (int kt = 0; kt < 5; ++kt)
                        #pragma unroll
                        for (int g = 0; g < 4; ++g) {
                            short8 w = *(const short8*)
                                &Wlds[(g * 16 + lrow) * KS0 + kt * 32 + lk8];
                            acc[g] = __builtin_amdgcn_mfma_f32_16x16x32_bf16(
                                xv[kt], w, acc[g], 0, 0, 0);
                        }
                }
                #pragma unroll
                for (int kt = 0; kt < 8; ++kt) {
                    short8 a = *(const short8*)&hs[arow * HS0 + kt * 32 + lk8];
                    #pragma unroll
                    for (int g = 0; g < 4; ++g) {
                        short8 w = *(const short8*)
                            &Wlds[(g * 16 + lrow) * KS0 + (5 + kt) * 32 + lk8];
                        acc[g] = __builtin_amdgcn_mfma_f32_16x16x32_bf16(
                            a, w, acc[g], 0, 0, 0);
                    }
                }
            } else {
                #pragma unroll
                for (int kt = 0; kt < 16; ++kt) {
                    short8 a = *(const short8*)&hs[arow * HS1 + kt * 32 + lk8];
                    #pragma unroll
                    for (int g = 0; g < 4; ++g) {
                        short8 w = *(const short8*)
                            &Wlds[(g * 16 + lrow) * KS1 + kt * 32 + lk8];
                        acc[g] = __builtin_amdgcn_mfma_f32_16x16x32_bf16(
                            a, w, acc[g], 0, 0, 0);
                    }
                }
            }

            // ---- gates fused in-lane (4 rows per lane) ----
            unsigned short hu[4];
            #pragma unroll
            for (int r = 0; r < 4; ++r) {
                float zi = acc[0][r] + br[ph][0];
                float zf = acc[1][r] + br[ph][1];
                float zg = acc[2][r] + br[ph][2];
                float zo = acc[3][r] + br[ph][3];
                float ig = fsigm(zi), fg = fsigm(zf), og = fsigm(zo);
                float cn = fg * creg[r] + ig * ftanh(zg);
                creg[r] = cn;
                union { __hip_bfloat16 b; unsigned short u; } cvt;
                cvt.b = __float2bfloat16(og * ftanh(cn));
                hu[r] = cvt.u;
            }

            // ---- in-wave transpose -> u64 packets; publish + poison ----
            // lane g16*16+m owns packet (row = mt*16 + g16*4 + (m>>2),
            // cols 4(m&3)..4(m&3)+3), gathered from lanes g16*16+4(m&3)+i.
            {
                const int m = lane & 15, g16 = lane >> 4;
                const int srcbase = g16 * 16 + 4 * (m & 3);
                const int myslot = m >> 2;
                unsigned short pa = 0, pb = 0, pc = 0, pd = 0;
                #pragma unroll
                for (int rr = 0; rr < 4; ++rr) {
                    int q0 = __shfl((int)hu[rr], srcbase + 0, 64);
                    int q1 = __shfl((int)hu[rr], srcbase + 1, 64);
                    int q2 = __shfl((int)hu[rr], srcbase + 2, 64);
                    int q3 = __shfl((int)hu[rr], srcbase + 3, 64);
                    if (myslot == rr) {
                        pa = (unsigned short)q0; pb = (unsigned short)q1;
                        pc = (unsigned short)q2; pd = (unsigned short)q3;
                    }
                }
                u64 pkt = (u64)pa | ((u64)pb << 16) | ((u64)pc << 32)
                        | ((u64)pd << 48);
                const int prow = mt * 16 + g16 * 4 + myslot;   // 0..31
                const int pq = m & 3;
                astore((u64*)(ringw + (size_t)(s & (RING - 1)) * SLOT_E)
                       + prow * 64 + ct * 4 + pq, pkt);
                if (layer == 1 && s >= 256)
                    *(u64*)&h1all[((size_t)(s - 256) * BB + xg * ROWS + prow) * HH
                                  + ct * 16 + pq * 4] = pkt;
                astore((u64*)(ringw + (size_t)((s + PO) & (RING - 1)) * SLOT_E)
                       + prow * 64 + ct * 4 + pq, POISON64);
            }
        }
    }
}

// ---------------- MFMA emit: logits + log_softmax ----------------
__global__ __launch_bounds__(256) void emit_mfma(
    const __hip_bfloat16* __restrict__ h1all,
    const __hip_bfloat16* __restrict__ lW,
    const float* __restrict__ lb,
    float* __restrict__ out) {
    __shared__ float lbs[160];
    const int tid = threadIdx.x;
    const int wv = tid >> 6, lane = tid & 63;
    const int lrow = lane & 15, lk8 = (lane >> 4) * 8, crow = (lane >> 4) * 4;
    const int row0 = blockIdx.x * 64;
    if (tid < 160) lbs[tid] = lb[tid];
    __syncthreads();

    f32x4 acc[10];
    #pragma unroll
    for (int f = 0; f < 10; ++f) acc[f] = (f32x4){0.f, 0.f, 0.f, 0.f};
    const int arow = row0 + wv * 16 + lrow;
    #pragma unroll
    for (int kt = 0; kt < 8; ++kt) {
        short8 a = *reinterpret_cast<const short8*>(
            &h1all[(size_t)arow * HH + kt * 32 + lk8]);
        #pragma unroll
        for (int f = 0; f < 10; ++f) {
            short8 w = *reinterpret_cast<const short8*>(
                &lW[(size_t)(f * 16 + lrow) * HH + kt * 32 + lk8]);
            acc[f] = __builtin_amdgcn_mfma_f32_16x16x32_bf16(a, w, acc[f], 0, 0, 0);
        }
    }
    #pragma unroll
    for (int r = 0; r < 4; ++r) {
        float m = -3.0e38f;
        #pragma unroll
        for (int f = 0; f < 10; ++f) m = fmaxf(m, acc[f][r] + lbs[f * 16 + lrow]);
        #pragma unroll
        for (int d = 1; d < 16; d <<= 1) m = fmaxf(m, __shfl_xor(m, d, 64));
        float ss = 0.f;
        #pragma unroll
        for (int f = 0; f < 10; ++f) ss += __expf(acc[f][r] + lbs[f * 16 + lrow] - m);
        #pragma unroll
        for (int d = 1; d < 16; d <<= 1) ss += __shfl_xor(ss, d, 64);
        float lse = m + logf(ss);
        int grow = row0 + wv * 16 + crow + r;
        #pragma unroll
        for (int f = 0; f < 9; ++f) {
            int j = f * 16 + lrow;
            if (j < DD)
                out[(size_t)grow * DD + j] = acc[f][r] + lbs[j] - lse;
        }
    }
}

extern "C" void kernel_launch(void* const* d_in, const int* in_sizes, int n_in,
                              void* d_out, int out_size, void* d_ws, size_t ws_size,
                              hipStream_t stream) {
    const float* X     = (const float*)d_in[0];
    const float* Y     = (const float*)d_in[1];
    const float* eWih0 = (const float*)d_in[2];
    const float* eWhh0 = (const float*)d_in[3];
    const float* ebih0 = (const float*)d_in[4];
    const float* ebhh0 = (const float*)d_in[5];
    const float* eWih1 = (const float*)d_in[6];
    const float* eWhh1 = (const float*)d_in[7];
    const float* ebih1 = (const float*)d_in[8];
    const float* ebhh1 = (const float*)d_in[9];
    const float* dWih0 = (const float*)d_in[10];
    const float* dWhh0 = (const float*)d_in[11];
    const float* dbih0 = (const float*)d_in[12];
    const float* dbhh0 = (const float*)d_in[13];
    const float* dWih1 = (const float*)d_in[14];
    const float* dWhh1 = (const float*)d_in[15];
    const float* dbih1 = (const float*)d_in[16];
    const float* dbhh1 = (const float*)d_in[17];
    const float* linW  = (const float*)d_in[18];
    const float* linb  = (const float*)d_in[19];
    float* out = (float*)d_out;

    __hip_bfloat16* wsb = (__hip_bfloat16*)d_ws;
    float* freg  = (float*)(wsb + OFF_BF16_END);
    float* bsum  = freg;                       // 4096 f32
    float* linbp = freg + 4096;                // 192
    int*   acks  = (int*)(freg + 4096 + 192);  // 256 ints (128B/group)

    pack_w0<<<dim3(1664), dim3(256), 0, stream>>>(eWih0, eWhh0, wsb + OFF_W0E);
    pack_w0<<<dim3(1664), dim3(256), 0, stream>>>(dWih0, dWhh0, wsb + OFF_W0D);
    pack_w1<<<dim3(2048), dim3(256), 0, stream>>>(eWih1, eWhh1, wsb + OFF_W1E);
    pack_w1<<<dim3(2048), dim3(256), 0, stream>>>(dWih1, dWhh1, wsb + OFF_W1D);
    pack_bias<<<dim3(4), dim3(256), 0, stream>>>(ebih0, ebhh0, bsum + 0);
    pack_bias<<<dim3(4), dim3(256), 0, stream>>>(ebih1, ebhh1, bsum + 1024);
    pack_bias<<<dim3(4), dim3(256), 0, stream>>>(dbih0, dbhh0, bsum + 2048);
    pack_bias<<<dim3(4), dim3(256), 0, stream>>>(dbih1, dbhh1, bsum + 3072);
    pack_xbf<<<dim3(81920), dim3(256), 0, stream>>>(X, Y, wsb + OFF_XBF);
    pack_linw<<<dim3(160), dim3(256), 0, stream>>>(linW, wsb + OFF_LW);
    pack_linb<<<dim3(1), dim3(256), 0, stream>>>(linb, linbp);
    init_rings<<<dim3(2048), dim3(256), 0, stream>>>((u64*)(wsb + OFF_H0R), acks);

    hipFuncSetAttribute((const void*)lstm_persistent,
                        hipFuncAttributeMaxDynamicSharedMemorySize, LDS_TOTAL);
    lstm_persistent<<<dim3(256), dim3(512), LDS_TOTAL, stream>>>(
        wsb, bsum, wsb + OFF_H0R, wsb + OFF_H1R, wsb + OFF_H1A, acks);

    emit_mfma<<<dim3(1024), dim3(256), 0, stream>>>(wsb + OFF_H1A, wsb + OFF_LW,
                                                    linbp, out);
}